// Round 4
// baseline (327.461 us; speedup 1.0000x reference)
//
#include <hip/hip_runtime.h>
#include <hip/hip_bf16.h>

#define N_NODES 100000
#define N_PAD 100032         // 1563 blocks * 64 rows
#define N_EDGES 600000
#define CH 128
#define N_GRAPHS 100
#define BN_EPS 1e-5f
#define NCHUNK 391           // ceil(N_NODES/256)
#define NBUCKET 64

typedef __bf16 bf16x8 __attribute__((ext_vector_type(8)));
typedef float f32x4 __attribute__((ext_vector_type(4)));

__device__ __forceinline__ ushort f2bf(float f) {
    union { float f; unsigned u; } x; x.f = f;
    unsigned u = x.u;
    unsigned r = (u + 0x7fffu + ((u >> 16) & 1u)) >> 16;
    return (ushort)r;
}
__device__ __forceinline__ float bf2f(ushort u) {
    union { unsigned u; float f; } x; x.u = ((unsigned)u) << 16;
    return x.f;
}

// ---------------------------------------------------------------------------
// CSR build
// ---------------------------------------------------------------------------
__global__ __launch_bounds__(256) void k_hist(const int* __restrict__ dst, int* __restrict__ cnt) {
    int e = blockIdx.x * 256 + threadIdx.x;
    if (e < N_EDGES) atomicAdd(&cnt[dst[e]], 1);
}

// one-kernel offsets: block-local scan + atomic block base (CSR bucket order
// is arrival-ordered -> still a valid CSR; gather uses offs[n]+cnt[n]).
__global__ __launch_bounds__(256) void k_blockoffs(const int* __restrict__ cnt,
        int* __restrict__ gcursor, int* __restrict__ offs, int* __restrict__ cursor) {
    __shared__ int sm[256];
    __shared__ int base;
    int t = threadIdx.x;
    int i = blockIdx.x * 256 + t;
    int v = (i < N_NODES) ? cnt[i] : 0;
    sm[t] = v; __syncthreads();
    for (int off = 1; off < 256; off <<= 1) {
        int add = (t >= off) ? sm[t - off] : 0;
        __syncthreads();
        sm[t] += add;
        __syncthreads();
    }
    if (t == 255) base = atomicAdd(gcursor, sm[255]);
    __syncthreads();
    if (i < N_NODES) {
        int start = base + sm[t] - v;
        offs[i] = start;
        cursor[i] = start;
    }
}

__global__ __launch_bounds__(256) void k_fill(const int* __restrict__ src, const int* __restrict__ dst,
        int* __restrict__ cursor, int* __restrict__ esrc) {
    int e = blockIdx.x * 256 + threadIdx.x;
    if (e < N_EDGES) {
        int p = atomicAdd(&cursor[dst[e]], 1);
        esrc[p] = src[e];
    }
}

// ---------------------------------------------------------------------------
// W [k][o] f32 -> Wt [o][k] bf16
// ---------------------------------------------------------------------------
__global__ __launch_bounds__(256) void k_convW(const float* __restrict__ W, ushort* __restrict__ Wt) {
    int t = blockIdx.x * 256 + threadIdx.x;       // 16384
    int k = t >> 7, o = t & 127;
    Wt[o * CH + k] = f2bf(W[t]);
}

// ---------------------------------------------------------------------------
// xh[n] = bf16(h[n] * norm[n])  -- halves gather row traffic
// ---------------------------------------------------------------------------
__global__ __launch_bounds__(256) void k_prescale(const float* __restrict__ h,
        const float* __restrict__ norm, ushort* __restrict__ xh) {
    int t = blockIdx.x * 256 + threadIdx.x;   // N_NODES*16
    int n = t >> 4, c = (t & 15) << 3;
    if (n >= N_NODES) return;
    float nm = norm[n];
    float4 a = *(const float4*)(h + (size_t)n * CH + c);
    float4 d = *(const float4*)(h + (size_t)n * CH + c + 4);
    uint4 o;
    o.x = (unsigned)f2bf(a.x * nm) | ((unsigned)f2bf(a.y * nm) << 16);
    o.y = (unsigned)f2bf(a.z * nm) | ((unsigned)f2bf(a.w * nm) << 16);
    o.z = (unsigned)f2bf(d.x * nm) | ((unsigned)f2bf(d.y * nm) << 16);
    o.w = (unsigned)f2bf(d.z * nm) | ((unsigned)f2bf(d.w * nm) << 16);
    *(uint4*)(xh + (size_t)n * CH + c) = o;
}

// ---------------------------------------------------------------------------
// Fused SpMM-gather + MFMA GEMM + bias/relu + BN partial stats.
// Block 256 -> 64 rows. Gather: 16 lanes/node, f32 accumulate, bf16 to LDS
// (row stride 136 ushort = 272 B -> 2-way bank aliasing, free).
// GEMM: wave w does rows w*16..w*16+15 x all 128 cols, A from LDS, B=Wt global.
// ---------------------------------------------------------------------------
__global__ __launch_bounds__(256) void k_spmm_gemm(const ushort* __restrict__ xh,
        const float* __restrict__ norm, const int* __restrict__ offs,
        const int* __restrict__ cnt, const int* __restrict__ esrc,
        const ushort* __restrict__ Wt, const float* __restrict__ bias,
        float* __restrict__ y, float* __restrict__ psum, float* __restrict__ psq) {
    __shared__ ushort xs[64][136];   // 17408 B

    int tid = threadIdx.x;
    int n0b = blockIdx.x * 64;

    // ---- gather phase: 4 passes x 16 nodes, lane handles 8 channels ----
    int c = (tid & 15) << 3;
    #pragma unroll
    for (int p = 0; p < 4; p++) {
        int r = p * 16 + (tid >> 4);
        int n = n0b + r;
        float acc[8] = {0.f, 0.f, 0.f, 0.f, 0.f, 0.f, 0.f, 0.f};
        float nn = 0.f;
        if (n < N_NODES) {
            nn = norm[n];
            int j0 = offs[n], e = cnt[n];
            for (int j = 0; j < e; j++) {
                int s = esrc[j0 + j];
                uint4 v = *(const uint4*)(xh + (size_t)s * CH + c);
                acc[0] += __builtin_bit_cast(float, v.x << 16);
                acc[1] += __builtin_bit_cast(float, v.x & 0xffff0000u);
                acc[2] += __builtin_bit_cast(float, v.y << 16);
                acc[3] += __builtin_bit_cast(float, v.y & 0xffff0000u);
                acc[4] += __builtin_bit_cast(float, v.z << 16);
                acc[5] += __builtin_bit_cast(float, v.z & 0xffff0000u);
                acc[6] += __builtin_bit_cast(float, v.w << 16);
                acc[7] += __builtin_bit_cast(float, v.w & 0xffff0000u);
            }
        }
        uint4 o;
        o.x = (unsigned)f2bf(acc[0] * nn) | ((unsigned)f2bf(acc[1] * nn) << 16);
        o.y = (unsigned)f2bf(acc[2] * nn) | ((unsigned)f2bf(acc[3] * nn) << 16);
        o.z = (unsigned)f2bf(acc[4] * nn) | ((unsigned)f2bf(acc[5] * nn) << 16);
        o.w = (unsigned)f2bf(acc[6] * nn) | ((unsigned)f2bf(acc[7] * nn) << 16);
        *(uint4*)&xs[r][c] = o;
    }
    __syncthreads();

    // ---- MFMA phase ----
    int w = tid >> 6, L = tid & 63;
    int c15 = L & 15, quad = L >> 4;
    size_t n0 = (size_t)n0b + w * 16;

    f32x4 acc2[8] = {};
    #pragma unroll
    for (int kt = 0; kt < 4; kt++) {
        bf16x8 a = *(const bf16x8*)&xs[w * 16 + c15][kt * 32 + quad * 8];
        #pragma unroll
        for (int ot = 0; ot < 8; ot++) {
            bf16x8 b = *(const bf16x8*)(Wt + (size_t)(ot * 16 + c15) * CH + kt * 32 + quad * 8);
            acc2[ot] = __builtin_amdgcn_mfma_f32_16x16x32_bf16(a, b, acc2[ot], 0, 0, 0);
        }
    }

    // ---- epilogue: bias + relu + store + stats (registers first) ----
    float sArr[8], qArr[8];
    #pragma unroll
    for (int ot = 0; ot < 8; ot++) {
        int col = ot * 16 + c15;
        float bv = bias[col];
        float s_ = 0.f, q_ = 0.f;
        #pragma unroll
        for (int r = 0; r < 4; r++) {
            size_t n = n0 + quad * 4 + r;
            float v = fmaxf(acc2[ot][r] + bv, 0.f);
            if (n < N_NODES) {
                y[n * CH + col] = v;
                s_ += v; q_ += v * v;
            }
        }
        sArr[ot] = s_; qArr[ot] = q_;
    }

    __syncthreads();                       // xs reads done -> safe to reuse
    float* red = (float*)&xs[0][0];        // need 16 KB, have 17408 B
    #pragma unroll
    for (int ot = 0; ot < 8; ot++) {
        red[ot * 256 + tid] = sArr[ot];
        red[2048 + ot * 256 + tid] = qArr[ot];
    }
    __syncthreads();

    if (tid < 128) {
        int ot = tid >> 4, cc = tid & 15;
        int col = ot * 16 + cc;
        float S = 0.f, Q = 0.f;
        #pragma unroll
        for (int g = 0; g < 16; g++) {
            int sl = (g >> 2) * 64 + (g & 3) * 16 + cc;
            S += red[ot * 256 + sl];
            Q += red[2048 + ot * 256 + sl];
        }
        int bucket = blockIdx.x & (NBUCKET - 1);
        atomicAdd(&psum[bucket * CH + col], S);
        atomicAdd(&psq[bucket * CH + col], Q);
    }
}

// ---------------------------------------------------------------------------
__global__ void k_finalize(const float* __restrict__ psum, const float* __restrict__ psq,
        const float* __restrict__ gamma, const float* __restrict__ beta,
        float* __restrict__ scale, float* __restrict__ shift) {
    int t = threadIdx.x;   // 128
    float S = 0.f, Q = 0.f;
    for (int g = 0; g < NBUCKET; g++) { S += psum[g * CH + t]; Q += psq[g * CH + t]; }
    const float invN = 1.f / (float)N_NODES;
    float mean = S * invN;
    float var  = Q * invN - mean * mean;
    float sc   = gamma[t] * rsqrtf(var + BN_EPS);
    scale[t] = sc;
    shift[t] = beta[t] - mean * sc;
}

// ---------------------------------------------------------------------------
// BN apply (in-place) + per-graph pooling (sorted gids -> run-length atomics)
// ---------------------------------------------------------------------------
#define PR 64
__global__ __launch_bounds__(256) void k_pool(float* __restrict__ y, const int* __restrict__ gids,
        const float* __restrict__ scale, const float* __restrict__ shift, float* __restrict__ phis) {
    int tid = threadIdx.x;
    int cl = tid & 31, rl = tid >> 5;
    int c = cl * 4;
    int r0 = blockIdx.x * PR;
    float4 sc = *(const float4*)(scale + c);
    float4 sh = *(const float4*)(shift + c);
    float4 local = make_float4(0.f, 0.f, 0.f, 0.f);
    int cur = -1;
    #pragma unroll
    for (int j = 0; j < 8; j++) {
        int r = r0 + j * 8 + rl;
        if (r >= N_NODES) break;
        int g = gids[r];
        if (g != cur) {
            if (cur >= 0) {
                atomicAdd(&phis[(size_t)cur * CH + c + 0], local.x);
                atomicAdd(&phis[(size_t)cur * CH + c + 1], local.y);
                atomicAdd(&phis[(size_t)cur * CH + c + 2], local.z);
                atomicAdd(&phis[(size_t)cur * CH + c + 3], local.w);
            }
            local = make_float4(0.f, 0.f, 0.f, 0.f);
            cur = g;
        }
        float4 v = *(float4*)(y + (size_t)r * CH + c);
        v.x = fmaf(v.x, sc.x, sh.x);
        v.y = fmaf(v.y, sc.y, sh.y);
        v.z = fmaf(v.z, sc.z, sh.z);
        v.w = fmaf(v.w, sc.w, sh.w);
        *(float4*)(y + (size_t)r * CH + c) = v;
        local.x += v.x; local.y += v.y; local.z += v.z; local.w += v.w;
    }
    if (cur >= 0) {
        atomicAdd(&phis[(size_t)cur * CH + c + 0], local.x);
        atomicAdd(&phis[(size_t)cur * CH + c + 1], local.y);
        atomicAdd(&phis[(size_t)cur * CH + c + 2], local.z);
        atomicAdd(&phis[(size_t)cur * CH + c + 3], local.w);
    }
}

// ---------------------------------------------------------------------------
extern "C" void kernel_launch(void* const* d_in, const int* in_sizes, int n_in,
                              void* d_out, int out_size, void* d_ws, size_t ws_size,
                              hipStream_t stream)
{
    const float* h     = (const float*)d_in[0];
    const float* norm  = (const float*)d_in[1];
    const float* W     = (const float*)d_in[2];
    const float* b     = (const float*)d_in[3];
    const float* gamma = (const float*)d_in[4];
    const float* beta  = (const float*)d_in[5];
    const int*   src   = (const int*)d_in[6];
    const int*   dst   = (const int*)d_in[7];
    const int*   gids  = (const int*)d_in[8];

    float* x_out = (float*)d_out;                       // [N,128]
    float* phis  = x_out + (size_t)N_NODES * CH;        // [100,128]

    ushort* xh     = (ushort*)d_ws;                     // [N,128] bf16 h*norm
    ushort* Wt     = xh + (size_t)N_NODES * CH;         // [128,128] bf16 W^T
    int*   cnt     = (int*)(Wt + CH * CH);              // [N]
    int*   gcursor = cnt + N_NODES;                     // [1]
    int*   offs    = gcursor + 1;                       // [N]
    int*   cursor  = offs + N_NODES;                    // [N]
    int*   esrc    = cursor + N_NODES;                  // [E]
    float* psum    = (float*)(esrc + N_EDGES);          // [64,128]
    float* psq     = psum + NBUCKET * CH;               // [64,128]
    float* scale   = psq + NBUCKET * CH;                // [128]
    float* shift   = scale + CH;                        // [128]

    hipMemsetAsync(cnt, 0, (size_t)(N_NODES + 1) * sizeof(int), stream);  // cnt + gcursor
    hipMemsetAsync(psum, 0, 2 * NBUCKET * CH * sizeof(float), stream);
    hipMemsetAsync(phis, 0, (size_t)N_GRAPHS * CH * sizeof(float), stream);

    k_hist<<<(N_EDGES + 255) / 256, 256, 0, stream>>>(dst, cnt);
    k_blockoffs<<<NCHUNK, 256, 0, stream>>>(cnt, gcursor, offs, cursor);
    k_fill<<<(N_EDGES + 255) / 256, 256, 0, stream>>>(src, dst, cursor, esrc);
    k_convW<<<64, 256, 0, stream>>>(W, Wt);
    k_prescale<<<(N_NODES * 16 + 255) / 256, 256, 0, stream>>>(h, norm, xh);
    k_spmm_gemm<<<N_PAD / 64, 256, 0, stream>>>(xh, norm, offs, cnt, esrc, Wt, b, x_out, psum, psq);
    k_finalize<<<1, 128, 0, stream>>>(psum, psq, gamma, beta, scale, shift);
    k_pool<<<(N_NODES + PR - 1) / PR, 256, 0, stream>>>(x_out, gids, scale, shift, phis);
}

// Round 5
// 311.271 us; speedup vs baseline: 1.0520x; 1.0520x over previous
//
#include <hip/hip_runtime.h>
#include <hip/hip_bf16.h>

#define N_NODES 100000
#define N_PAD 100032         // 1563 blocks * 64 rows
#define N_EDGES 600000
#define CH 128
#define N_GRAPHS 100
#define BN_EPS 1e-5f
#define NCHUNK 391           // ceil(N_NODES/256)
#define NBUCKET 64

typedef __bf16 bf16x8 __attribute__((ext_vector_type(8)));
typedef float f32x4 __attribute__((ext_vector_type(4)));

__device__ __forceinline__ ushort f2bf(float f) {
    union { float f; unsigned u; } x; x.f = f;
    unsigned u = x.u;
    unsigned r = (u + 0x7fffu + ((u >> 16) & 1u)) >> 16;
    return (ushort)r;
}
__device__ __forceinline__ float bflo(unsigned p) { return __builtin_bit_cast(float, p << 16); }
__device__ __forceinline__ float bfhi(unsigned p) { return __builtin_bit_cast(float, p & 0xffff0000u); }

// ---------------------------------------------------------------------------
// CSR build
// ---------------------------------------------------------------------------
__global__ __launch_bounds__(256) void k_hist(const int* __restrict__ dst, int* __restrict__ cnt) {
    int e = blockIdx.x * 256 + threadIdx.x;
    if (e < N_EDGES) atomicAdd(&cnt[dst[e]], 1);
}

// block-local scan + atomic block base (arrival-ordered CSR; gather uses cnt[])
__global__ __launch_bounds__(256) void k_blockoffs(const int* __restrict__ cnt,
        int* __restrict__ gcursor, int* __restrict__ offs, int* __restrict__ cursor) {
    __shared__ int sm[256];
    __shared__ int base;
    int t = threadIdx.x;
    int i = blockIdx.x * 256 + t;
    int v = (i < N_NODES) ? cnt[i] : 0;
    sm[t] = v; __syncthreads();
    for (int off = 1; off < 256; off <<= 1) {
        int add = (t >= off) ? sm[t - off] : 0;
        __syncthreads();
        sm[t] += add;
        __syncthreads();
    }
    if (t == 255) base = atomicAdd(gcursor, sm[255]);
    __syncthreads();
    if (i < N_NODES) {
        int start = base + sm[t] - v;
        offs[i] = start;
        cursor[i] = start;
    }
}

__global__ __launch_bounds__(256) void k_fill(const int* __restrict__ src, const int* __restrict__ dst,
        int* __restrict__ cursor, int* __restrict__ esrc) {
    int e = blockIdx.x * 256 + threadIdx.x;
    if (e < N_EDGES) {
        int p = atomicAdd(&cursor[dst[e]], 1);
        esrc[p] = src[e];
    }
}

// ---------------------------------------------------------------------------
// W [k][o] f32 -> Wt [o][k] bf16
// ---------------------------------------------------------------------------
__global__ __launch_bounds__(256) void k_convW(const float* __restrict__ W, ushort* __restrict__ Wt) {
    int t = blockIdx.x * 256 + threadIdx.x;       // 16384
    int k = t >> 7, o = t & 127;
    Wt[o * CH + k] = f2bf(W[t]);
}

// ---------------------------------------------------------------------------
// xh[n] = bf16(h[n] * norm[n])
// ---------------------------------------------------------------------------
__global__ __launch_bounds__(256) void k_prescale(const float* __restrict__ h,
        const float* __restrict__ norm, ushort* __restrict__ xh) {
    int t = blockIdx.x * 256 + threadIdx.x;   // N_NODES*16
    int n = t >> 4, c = (t & 15) << 3;
    if (n >= N_NODES) return;
    float nm = norm[n];
    float4 a = *(const float4*)(h + (size_t)n * CH + c);
    float4 d = *(const float4*)(h + (size_t)n * CH + c + 4);
    uint4 o;
    o.x = (unsigned)f2bf(a.x * nm) | ((unsigned)f2bf(a.y * nm) << 16);
    o.y = (unsigned)f2bf(a.z * nm) | ((unsigned)f2bf(a.w * nm) << 16);
    o.z = (unsigned)f2bf(d.x * nm) | ((unsigned)f2bf(d.y * nm) << 16);
    o.w = (unsigned)f2bf(d.z * nm) | ((unsigned)f2bf(d.w * nm) << 16);
    *(uint4*)(xh + (size_t)n * CH + c) = o;
}

// ---------------------------------------------------------------------------
// Gather (ILP version): x2[n] = bf16( norm[n] * sum_in xh[s] ).
// 32 lanes/node, 4 ch/lane (uint2 = 8B). Edge loop unrolled x4 with
// independent index+row loads -> short dependence chains. No LDS, no barrier.
// ---------------------------------------------------------------------------
__global__ __launch_bounds__(256) void k_gather(const ushort* __restrict__ xh,
        const float* __restrict__ norm, const int* __restrict__ offs,
        const int* __restrict__ cnt, const int* __restrict__ esrc,
        ushort* __restrict__ x2) {
    int t = blockIdx.x * 256 + threadIdx.x;
    int n = t >> 5;
    int c = (t & 31) << 2;                 // 4 channels
    if (n >= N_PAD) return;
    int j0 = 0, e = 0;
    float nn = 0.f;
    if (n < N_NODES) { j0 = offs[n]; e = cnt[n]; nn = norm[n]; }
    float a0 = 0.f, a1 = 0.f, a2 = 0.f, a3 = 0.f;
    int j = 0;
    for (; j + 4 <= e; j += 4) {
        int s0 = esrc[j0 + j], s1 = esrc[j0 + j + 1];
        int s2 = esrc[j0 + j + 2], s3 = esrc[j0 + j + 3];
        uint2 v0 = *(const uint2*)(xh + (size_t)s0 * CH + c);
        uint2 v1 = *(const uint2*)(xh + (size_t)s1 * CH + c);
        uint2 v2 = *(const uint2*)(xh + (size_t)s2 * CH + c);
        uint2 v3 = *(const uint2*)(xh + (size_t)s3 * CH + c);
        a0 += bflo(v0.x) + bflo(v1.x) + bflo(v2.x) + bflo(v3.x);
        a1 += bfhi(v0.x) + bfhi(v1.x) + bfhi(v2.x) + bfhi(v3.x);
        a2 += bflo(v0.y) + bflo(v1.y) + bflo(v2.y) + bflo(v3.y);
        a3 += bfhi(v0.y) + bfhi(v1.y) + bfhi(v2.y) + bfhi(v3.y);
    }
    for (; j < e; j++) {
        int s = esrc[j0 + j];
        uint2 v = *(const uint2*)(xh + (size_t)s * CH + c);
        a0 += bflo(v.x); a1 += bfhi(v.x);
        a2 += bflo(v.y); a3 += bfhi(v.y);
    }
    ushort4 o;
    o.x = f2bf(a0 * nn); o.y = f2bf(a1 * nn);
    o.z = f2bf(a2 * nn); o.w = f2bf(a3 * nn);
    *(ushort4*)(x2 + (size_t)n * CH + c) = o;
}

// ---------------------------------------------------------------------------
// MFMA GEMM: y = relu(x2 @ W + b), fused BN partial stats (r3-verified).
// ---------------------------------------------------------------------------
__global__ __launch_bounds__(256) void k_gemm(const ushort* __restrict__ x2,
        const ushort* __restrict__ Wt, const float* __restrict__ bias,
        float* __restrict__ y, float* __restrict__ psum, float* __restrict__ psq) {
    __shared__ float smS[8 * 256];
    __shared__ float smQ[8 * 256];

    int tid = threadIdx.x;
    int w = tid >> 6, L = tid & 63;
    int c15 = L & 15, quad = L >> 4;
    size_t n0 = (size_t)blockIdx.x * 64 + w * 16;

    const bf16x8* Arow = (const bf16x8*)(x2 + (n0 + c15) * CH);

    f32x4 acc[8] = {};
    #pragma unroll
    for (int kt = 0; kt < 4; kt++) {
        bf16x8 a = Arow[kt * 4 + quad];
        #pragma unroll
        for (int ot = 0; ot < 8; ot++) {
            const bf16x8* Brow = (const bf16x8*)(Wt + (size_t)(ot * 16 + c15) * CH);
            bf16x8 b = Brow[kt * 4 + quad];
            acc[ot] = __builtin_amdgcn_mfma_f32_16x16x32_bf16(a, b, acc[ot], 0, 0, 0);
        }
    }

    #pragma unroll
    for (int ot = 0; ot < 8; ot++) {
        int col = ot * 16 + c15;
        float bv = bias[col];
        float s_ = 0.f, q_ = 0.f;
        #pragma unroll
        for (int r = 0; r < 4; r++) {
            size_t n = n0 + quad * 4 + r;
            float v = fmaxf(acc[ot][r] + bv, 0.f);
            if (n < N_NODES) {
                y[n * CH + col] = v;
                s_ += v; q_ += v * v;
            }
        }
        smS[ot * 256 + tid] = s_;
        smQ[ot * 256 + tid] = q_;
    }
    __syncthreads();

    if (tid < 128) {
        int ot = tid >> 4, cc = tid & 15;
        int col = ot * 16 + cc;
        float S = 0.f, Q = 0.f;
        #pragma unroll
        for (int g = 0; g < 16; g++) {
            int sl = (g >> 2) * 64 + (g & 3) * 16 + cc;
            S += smS[ot * 256 + sl];
            Q += smQ[ot * 256 + sl];
        }
        int bucket = blockIdx.x & (NBUCKET - 1);
        atomicAdd(&psum[bucket * CH + col], S);
        atomicAdd(&psq[bucket * CH + col], Q);
    }
}

// ---------------------------------------------------------------------------
__global__ void k_finalize(const float* __restrict__ psum, const float* __restrict__ psq,
        const float* __restrict__ gamma, const float* __restrict__ beta,
        float* __restrict__ scale, float* __restrict__ shift) {
    int t = threadIdx.x;   // 128
    float S = 0.f, Q = 0.f;
    for (int g = 0; g < NBUCKET; g++) { S += psum[g * CH + t]; Q += psq[g * CH + t]; }
    const float invN = 1.f / (float)N_NODES;
    float mean = S * invN;
    float var  = Q * invN - mean * mean;
    float sc   = gamma[t] * rsqrtf(var + BN_EPS);
    scale[t] = sc;
    shift[t] = beta[t] - mean * sc;
}

// ---------------------------------------------------------------------------
// BN apply (in-place) + per-graph pooling (sorted gids -> run-length atomics)
// ---------------------------------------------------------------------------
#define PR 64
__global__ __launch_bounds__(256) void k_pool(float* __restrict__ y, const int* __restrict__ gids,
        const float* __restrict__ scale, const float* __restrict__ shift, float* __restrict__ phis) {
    int tid = threadIdx.x;
    int cl = tid & 31, rl = tid >> 5;
    int c = cl * 4;
    int r0 = blockIdx.x * PR;
    float4 sc = *(const float4*)(scale + c);
    float4 sh = *(const float4*)(shift + c);
    float4 local = make_float4(0.f, 0.f, 0.f, 0.f);
    int cur = -1;
    #pragma unroll
    for (int j = 0; j < 8; j++) {
        int r = r0 + j * 8 + rl;
        if (r >= N_NODES) break;
        int g = gids[r];
        if (g != cur) {
            if (cur >= 0) {
                atomicAdd(&phis[(size_t)cur * CH + c + 0], local.x);
                atomicAdd(&phis[(size_t)cur * CH + c + 1], local.y);
                atomicAdd(&phis[(size_t)cur * CH + c + 2], local.z);
                atomicAdd(&phis[(size_t)cur * CH + c + 3], local.w);
            }
            local = make_float4(0.f, 0.f, 0.f, 0.f);
            cur = g;
        }
        float4 v = *(float4*)(y + (size_t)r * CH + c);
        v.x = fmaf(v.x, sc.x, sh.x);
        v.y = fmaf(v.y, sc.y, sh.y);
        v.z = fmaf(v.z, sc.z, sh.z);
        v.w = fmaf(v.w, sc.w, sh.w);
        *(float4*)(y + (size_t)r * CH + c) = v;
        local.x += v.x; local.y += v.y; local.z += v.z; local.w += v.w;
    }
    if (cur >= 0) {
        atomicAdd(&phis[(size_t)cur * CH + c + 0], local.x);
        atomicAdd(&phis[(size_t)cur * CH + c + 1], local.y);
        atomicAdd(&phis[(size_t)cur * CH + c + 2], local.z);
        atomicAdd(&phis[(size_t)cur * CH + c + 3], local.w);
    }
}

// ---------------------------------------------------------------------------
extern "C" void kernel_launch(void* const* d_in, const int* in_sizes, int n_in,
                              void* d_out, int out_size, void* d_ws, size_t ws_size,
                              hipStream_t stream)
{
    const float* h     = (const float*)d_in[0];
    const float* norm  = (const float*)d_in[1];
    const float* W     = (const float*)d_in[2];
    const float* b     = (const float*)d_in[3];
    const float* gamma = (const float*)d_in[4];
    const float* beta  = (const float*)d_in[5];
    const int*   src   = (const int*)d_in[6];
    const int*   dst   = (const int*)d_in[7];
    const int*   gids  = (const int*)d_in[8];

    float* x_out = (float*)d_out;                       // [N,128]
    float* phis  = x_out + (size_t)N_NODES * CH;        // [100,128]

    ushort* xh     = (ushort*)d_ws;                     // [N,128] bf16 h*norm
    ushort* x2     = xh + (size_t)N_NODES * CH;         // [N_PAD,128] bf16 agg
    ushort* Wt     = x2 + (size_t)N_PAD * CH;           // [128,128] bf16 W^T
    int*   cnt     = (int*)(Wt + CH * CH);              // [N]
    int*   gcursor = cnt + N_NODES;                     // [1]
    int*   offs    = gcursor + 1;                       // [N]
    int*   cursor  = offs + N_NODES;                    // [N]
    int*   esrc    = cursor + N_NODES;                  // [E]
    float* psum    = (float*)(esrc + N_EDGES);          // [64,128]
    float* psq     = psum + NBUCKET * CH;               // [64,128]
    float* scale   = psq + NBUCKET * CH;                // [128]
    float* shift   = scale + CH;                        // [128]

    hipMemsetAsync(cnt, 0, (size_t)(N_NODES + 1) * sizeof(int), stream);  // cnt + gcursor
    hipMemsetAsync(psum, 0, 2 * NBUCKET * CH * sizeof(float), stream);
    hipMemsetAsync(phis, 0, (size_t)N_GRAPHS * CH * sizeof(float), stream);

    k_hist<<<(N_EDGES + 255) / 256, 256, 0, stream>>>(dst, cnt);
    k_blockoffs<<<NCHUNK, 256, 0, stream>>>(cnt, gcursor, offs, cursor);
    k_fill<<<(N_EDGES + 255) / 256, 256, 0, stream>>>(src, dst, cursor, esrc);
    k_convW<<<64, 256, 0, stream>>>(W, Wt);
    k_prescale<<<(N_NODES * 16 + 255) / 256, 256, 0, stream>>>(h, norm, xh);
    k_gather<<<(N_PAD * 32) / 256, 256, 0, stream>>>(xh, norm, offs, cnt, esrc, x2);
    k_gemm<<<N_PAD / 64, 256, 0, stream>>>(x2, Wt, b, x_out, psum, psq);
    k_finalize<<<1, 128, 0, stream>>>(psum, psq, gamma, beta, scale, shift);
    k_pool<<<(N_NODES + PR - 1) / PR, 256, 0, stream>>>(x_out, gids, scale, shift, phis);
}

// Round 6
// 298.135 us; speedup vs baseline: 1.0984x; 1.0441x over previous
//
#include <hip/hip_runtime.h>
#include <hip/hip_bf16.h>

#define N_NODES 100000
#define N_PAD 100032         // 1563 blocks * 64 rows
#define N_EDGES 600000
#define CH 128
#define N_GRAPHS 100
#define BN_EPS 1e-5f
#define NCHUNK 391           // ceil(N_NODES/256)
#define NBUCKET 64
#define PHIB 8               // phi atomic bucket copies

typedef __bf16 bf16x8 __attribute__((ext_vector_type(8)));
typedef float f32x4 __attribute__((ext_vector_type(4)));

__device__ __forceinline__ ushort f2bf(float f) {
    union { float f; unsigned u; } x; x.f = f;
    unsigned u = x.u;
    unsigned r = (u + 0x7fffu + ((u >> 16) & 1u)) >> 16;
    return (ushort)r;
}
__device__ __forceinline__ float bflo(unsigned p) { return __builtin_bit_cast(float, p << 16); }
__device__ __forceinline__ float bfhi(unsigned p) { return __builtin_bit_cast(float, p & 0xffff0000u); }

// ---------------------------------------------------------------------------
// CSR build
// ---------------------------------------------------------------------------
__global__ __launch_bounds__(256) void k_hist(const int* __restrict__ dst, int* __restrict__ cnt) {
    int e = blockIdx.x * 256 + threadIdx.x;
    if (e < N_EDGES) atomicAdd(&cnt[dst[e]], 1);
}

__global__ __launch_bounds__(256) void k_blockoffs(const int* __restrict__ cnt,
        int* __restrict__ gcursor, int* __restrict__ offs, int* __restrict__ cursor) {
    __shared__ int sm[256];
    __shared__ int base;
    int t = threadIdx.x;
    int i = blockIdx.x * 256 + t;
    int v = (i < N_NODES) ? cnt[i] : 0;
    sm[t] = v; __syncthreads();
    for (int off = 1; off < 256; off <<= 1) {
        int add = (t >= off) ? sm[t - off] : 0;
        __syncthreads();
        sm[t] += add;
        __syncthreads();
    }
    if (t == 255) base = atomicAdd(gcursor, sm[255]);
    __syncthreads();
    if (i < N_NODES) {
        int start = base + sm[t] - v;
        offs[i] = start;
        cursor[i] = start;
    }
}

__global__ __launch_bounds__(256) void k_fill(const int* __restrict__ src, const int* __restrict__ dst,
        int* __restrict__ cursor, int* __restrict__ esrc) {
    int e = blockIdx.x * 256 + threadIdx.x;
    if (e < N_EDGES) {
        int p = atomicAdd(&cursor[dst[e]], 1);
        esrc[p] = src[e];
    }
}

// ---------------------------------------------------------------------------
__global__ __launch_bounds__(256) void k_convW(const float* __restrict__ W, ushort* __restrict__ Wt) {
    int t = blockIdx.x * 256 + threadIdx.x;       // 16384
    int k = t >> 7, o = t & 127;
    Wt[o * CH + k] = f2bf(W[t]);
}

// ---------------------------------------------------------------------------
__global__ __launch_bounds__(256) void k_prescale(const float* __restrict__ h,
        const float* __restrict__ norm, ushort* __restrict__ xh) {
    int t = blockIdx.x * 256 + threadIdx.x;   // N_NODES*16
    int n = t >> 4, c = (t & 15) << 3;
    if (n >= N_NODES) return;
    float nm = norm[n];
    float4 a = *(const float4*)(h + (size_t)n * CH + c);
    float4 d = *(const float4*)(h + (size_t)n * CH + c + 4);
    uint4 o;
    o.x = (unsigned)f2bf(a.x * nm) | ((unsigned)f2bf(a.y * nm) << 16);
    o.y = (unsigned)f2bf(a.z * nm) | ((unsigned)f2bf(a.w * nm) << 16);
    o.z = (unsigned)f2bf(d.x * nm) | ((unsigned)f2bf(d.y * nm) << 16);
    o.w = (unsigned)f2bf(d.z * nm) | ((unsigned)f2bf(d.w * nm) << 16);
    *(uint4*)(xh + (size_t)n * CH + c) = o;
}

// ---------------------------------------------------------------------------
// Gather: 16 lanes/node, 8 ch/lane (uint4 = 16B row segment). Edge loop
// unrolled x4 -> independent loads; no LDS, no barriers.
// ---------------------------------------------------------------------------
__global__ __launch_bounds__(256) void k_gather(const ushort* __restrict__ xh,
        const float* __restrict__ norm, const int* __restrict__ offs,
        const int* __restrict__ cnt, const int* __restrict__ esrc,
        ushort* __restrict__ x2) {
    int t = blockIdx.x * 256 + threadIdx.x;
    int n = t >> 4;
    int c = (t & 15) << 3;                 // 8 channels
    if (n >= N_PAD) return;
    int j0 = 0, e = 0;
    float nn = 0.f;
    if (n < N_NODES) { j0 = offs[n]; e = cnt[n]; nn = norm[n]; }
    float a0=0.f,a1=0.f,a2=0.f,a3=0.f,a4=0.f,a5=0.f,a6=0.f,a7=0.f;
    int j = 0;
    for (; j + 4 <= e; j += 4) {
        int s0 = esrc[j0 + j], s1 = esrc[j0 + j + 1];
        int s2 = esrc[j0 + j + 2], s3 = esrc[j0 + j + 3];
        uint4 v0 = *(const uint4*)(xh + (size_t)s0 * CH + c);
        uint4 v1 = *(const uint4*)(xh + (size_t)s1 * CH + c);
        uint4 v2 = *(const uint4*)(xh + (size_t)s2 * CH + c);
        uint4 v3 = *(const uint4*)(xh + (size_t)s3 * CH + c);
        a0 += bflo(v0.x) + bflo(v1.x) + bflo(v2.x) + bflo(v3.x);
        a1 += bfhi(v0.x) + bfhi(v1.x) + bfhi(v2.x) + bfhi(v3.x);
        a2 += bflo(v0.y) + bflo(v1.y) + bflo(v2.y) + bflo(v3.y);
        a3 += bfhi(v0.y) + bfhi(v1.y) + bfhi(v2.y) + bfhi(v3.y);
        a4 += bflo(v0.z) + bflo(v1.z) + bflo(v2.z) + bflo(v3.z);
        a5 += bfhi(v0.z) + bfhi(v1.z) + bfhi(v2.z) + bfhi(v3.z);
        a6 += bflo(v0.w) + bflo(v1.w) + bflo(v2.w) + bflo(v3.w);
        a7 += bfhi(v0.w) + bfhi(v1.w) + bfhi(v2.w) + bfhi(v3.w);
    }
    for (; j < e; j++) {
        int s = esrc[j0 + j];
        uint4 v = *(const uint4*)(xh + (size_t)s * CH + c);
        a0 += bflo(v.x); a1 += bfhi(v.x);
        a2 += bflo(v.y); a3 += bfhi(v.y);
        a4 += bflo(v.z); a5 += bfhi(v.z);
        a6 += bflo(v.w); a7 += bfhi(v.w);
    }
    uint4 o;
    o.x = (unsigned)f2bf(a0 * nn) | ((unsigned)f2bf(a1 * nn) << 16);
    o.y = (unsigned)f2bf(a2 * nn) | ((unsigned)f2bf(a3 * nn) << 16);
    o.z = (unsigned)f2bf(a4 * nn) | ((unsigned)f2bf(a5 * nn) << 16);
    o.w = (unsigned)f2bf(a6 * nn) | ((unsigned)f2bf(a7 * nn) << 16);
    *(uint4*)(x2 + (size_t)n * CH + c) = o;
}

// ---------------------------------------------------------------------------
// Pass A: MFMA GEMM, bias+relu, BN partial stats ONLY (no y store).
// ---------------------------------------------------------------------------
__global__ __launch_bounds__(256) void k_gemm_stats(const ushort* __restrict__ x2,
        const ushort* __restrict__ Wt, const float* __restrict__ bias,
        float* __restrict__ psum, float* __restrict__ psq) {
    __shared__ float smS[8 * 256];
    __shared__ float smQ[8 * 256];

    int tid = threadIdx.x;
    int w = tid >> 6, L = tid & 63;
    int c15 = L & 15, quad = L >> 4;
    size_t n0 = (size_t)blockIdx.x * 64 + w * 16;

    const bf16x8* Arow = (const bf16x8*)(x2 + (n0 + c15) * CH);

    f32x4 acc[8] = {};
    #pragma unroll
    for (int kt = 0; kt < 4; kt++) {
        bf16x8 a = Arow[kt * 4 + quad];
        #pragma unroll
        for (int ot = 0; ot < 8; ot++) {
            const bf16x8* Brow = (const bf16x8*)(Wt + (size_t)(ot * 16 + c15) * CH);
            bf16x8 b = Brow[kt * 4 + quad];
            acc[ot] = __builtin_amdgcn_mfma_f32_16x16x32_bf16(a, b, acc[ot], 0, 0, 0);
        }
    }

    #pragma unroll
    for (int ot = 0; ot < 8; ot++) {
        int col = ot * 16 + c15;
        float bv = bias[col];
        float s_ = 0.f, q_ = 0.f;
        #pragma unroll
        for (int r = 0; r < 4; r++) {
            size_t n = n0 + quad * 4 + r;
            float v = fmaxf(acc[ot][r] + bv, 0.f);
            if (n < N_NODES) { s_ += v; q_ += v * v; }
        }
        smS[ot * 256 + tid] = s_;
        smQ[ot * 256 + tid] = q_;
    }
    __syncthreads();

    if (tid < 128) {
        int ot = tid >> 4, cc = tid & 15;
        int col = ot * 16 + cc;
        float S = 0.f, Q = 0.f;
        #pragma unroll
        for (int g = 0; g < 16; g++) {
            int sl = (g >> 2) * 64 + (g & 3) * 16 + cc;
            S += smS[ot * 256 + sl];
            Q += smQ[ot * 256 + sl];
        }
        int bucket = blockIdx.x & (NBUCKET - 1);
        atomicAdd(&psum[bucket * CH + col], S);
        atomicAdd(&psq[bucket * CH + col], Q);
    }
}

// ---------------------------------------------------------------------------
__global__ void k_finalize(const float* __restrict__ psum, const float* __restrict__ psq,
        const float* __restrict__ gamma, const float* __restrict__ beta,
        float* __restrict__ scale, float* __restrict__ shift) {
    int t = threadIdx.x;   // 128
    float S = 0.f, Q = 0.f;
    for (int g = 0; g < NBUCKET; g++) { S += psum[g * CH + t]; Q += psq[g * CH + t]; }
    const float invN = 1.f / (float)N_NODES;
    float mean = S * invN;
    float var  = Q * invN - mean * mean;
    float sc   = gamma[t] * rsqrtf(var + BN_EPS);
    scale[t] = sc;
    shift[t] = beta[t] - mean * sc;
}

// ---------------------------------------------------------------------------
// Pass B: recompute MFMA, apply BN in registers, write final x once, and pool
// per-graph sums from registers. Sorted gids: wave-uniform fast path
// (cross-quad shfl_xor reduce -> 1 atomic/wave/col), run-length fallback.
// ---------------------------------------------------------------------------
__global__ __launch_bounds__(256) void k_gemm_out(const ushort* __restrict__ x2,
        const ushort* __restrict__ Wt, const float* __restrict__ bias,
        const float* __restrict__ scale, const float* __restrict__ shift,
        const int* __restrict__ gids, float* __restrict__ xout,
        float* __restrict__ phis_b) {
    int tid = threadIdx.x;
    int w = tid >> 6, L = tid & 63;
    int c15 = L & 15, quad = L >> 4;
    int n0 = blockIdx.x * 64 + w * 16;       // wave row base

    const bf16x8* Arow = (const bf16x8*)(x2 + (size_t)(n0 + c15) * CH);

    f32x4 acc[8] = {};
    #pragma unroll
    for (int kt = 0; kt < 4; kt++) {
        bf16x8 a = Arow[kt * 4 + quad];
        #pragma unroll
        for (int ot = 0; ot < 8; ot++) {
            const bf16x8* Brow = (const bf16x8*)(Wt + (size_t)(ot * 16 + c15) * CH);
            bf16x8 b = Brow[kt * 4 + quad];
            acc[ot] = __builtin_amdgcn_mfma_f32_16x16x32_bf16(a, b, acc[ot], 0, 0, 0);
        }
    }

    // bias + relu + BN, store x
    #pragma unroll
    for (int ot = 0; ot < 8; ot++) {
        int col = ot * 16 + c15;
        float bv = bias[col], sc = scale[col], sh = shift[col];
        #pragma unroll
        for (int r = 0; r < 4; r++) {
            int n = n0 + quad * 4 + r;
            float v = fmaf(fmaxf(acc[ot][r] + bv, 0.f), sc, sh);
            acc[ot][r] = v;
            if (n < N_NODES) xout[(size_t)n * CH + col] = v;
        }
    }

    float* pb = phis_b + (size_t)(blockIdx.x & (PHIB - 1)) * (N_GRAPHS * CH);

    if (n0 + 16 <= N_NODES && gids[n0] == gids[n0 + 15]) {
        // fast path: all 16 rows of this wave in one graph
        int g = gids[n0];
        #pragma unroll
        for (int ot = 0; ot < 8; ot++) {
            float v = acc[ot][0] + acc[ot][1] + acc[ot][2] + acc[ot][3];
            v += __shfl_xor(v, 16);
            v += __shfl_xor(v, 32);
            if (quad == 0) atomicAdd(&pb[g * CH + ot * 16 + c15], v);
        }
    } else {
        // slow path: per-lane run-length over its 4 rows
        float segv[8] = {};
        int gprev = -1;
        #pragma unroll
        for (int r = 0; r < 4; r++) {
            int n = n0 + quad * 4 + r;
            if (n >= N_NODES) break;
            int g = gids[n];
            if (g != gprev) {
                if (gprev >= 0) {
                    #pragma unroll
                    for (int ot = 0; ot < 8; ot++) {
                        atomicAdd(&pb[gprev * CH + ot * 16 + c15], segv[ot]);
                        segv[ot] = 0.f;
                    }
                }
                gprev = g;
            }
            #pragma unroll
            for (int ot = 0; ot < 8; ot++) segv[ot] += acc[ot][r];
        }
        if (gprev >= 0) {
            #pragma unroll
            for (int ot = 0; ot < 8; ot++)
                atomicAdd(&pb[gprev * CH + ot * 16 + c15], segv[ot]);
        }
    }
}

// ---------------------------------------------------------------------------
__global__ __launch_bounds__(256) void k_phifin(const float* __restrict__ phis_b,
        float* __restrict__ phis) {
    int t = blockIdx.x * 256 + threadIdx.x;   // 12800
    if (t >= N_GRAPHS * CH) return;
    float s = 0.f;
    #pragma unroll
    for (int k = 0; k < PHIB; k++) s += phis_b[(size_t)k * (N_GRAPHS * CH) + t];
    phis[t] = s;
}

// ---------------------------------------------------------------------------
extern "C" void kernel_launch(void* const* d_in, const int* in_sizes, int n_in,
                              void* d_out, int out_size, void* d_ws, size_t ws_size,
                              hipStream_t stream)
{
    const float* h     = (const float*)d_in[0];
    const float* norm  = (const float*)d_in[1];
    const float* W     = (const float*)d_in[2];
    const float* b     = (const float*)d_in[3];
    const float* gamma = (const float*)d_in[4];
    const float* beta  = (const float*)d_in[5];
    const int*   src   = (const int*)d_in[6];
    const int*   dst   = (const int*)d_in[7];
    const int*   gids  = (const int*)d_in[8];

    float* x_out = (float*)d_out;                       // [N,128]
    float* phis  = x_out + (size_t)N_NODES * CH;        // [100,128]

    ushort* xh     = (ushort*)d_ws;                     // [N,128] bf16 h*norm
    ushort* x2     = xh + (size_t)N_NODES * CH;         // [N_PAD,128] bf16 agg
    ushort* Wt     = x2 + (size_t)N_PAD * CH;           // [128,128] bf16 W^T
    int*   cnt     = (int*)(Wt + CH * CH);              // [N]
    int*   gcursor = cnt + N_NODES;                     // [1]
    int*   offs    = gcursor + 1;                       // [N]
    int*   cursor  = offs + N_NODES;                    // [N]
    int*   esrc    = cursor + N_NODES;                  // [E]
    float* psum    = (float*)(esrc + N_EDGES);          // [64,128]
    float* psq     = psum + NBUCKET * CH;               // [64,128]
    float* scale   = psq + NBUCKET * CH;                // [128]
    float* shift   = scale + CH;                        // [128]
    float* phis_b  = shift + CH;                        // [8,100,128]

    hipMemsetAsync(cnt, 0, (size_t)(N_NODES + 1) * sizeof(int), stream);  // cnt + gcursor
    hipMemsetAsync(psum, 0, 2 * NBUCKET * CH * sizeof(float), stream);
    hipMemsetAsync(phis_b, 0, (size_t)PHIB * N_GRAPHS * CH * sizeof(float), stream);

    k_hist<<<(N_EDGES + 255) / 256, 256, 0, stream>>>(dst, cnt);
    k_blockoffs<<<NCHUNK, 256, 0, stream>>>(cnt, gcursor, offs, cursor);
    k_fill<<<(N_EDGES + 255) / 256, 256, 0, stream>>>(src, dst, cursor, esrc);
    k_convW<<<64, 256, 0, stream>>>(W, Wt);
    k_prescale<<<(N_NODES * 16 + 255) / 256, 256, 0, stream>>>(h, norm, xh);
    k_gather<<<(N_PAD * 16) / 256, 256, 0, stream>>>(xh, norm, offs, cnt, esrc, x2);
    k_gemm_stats<<<N_PAD / 64, 256, 0, stream>>>(x2, Wt, b, psum, psq);
    k_finalize<<<1, 128, 0, stream>>>(psum, psq, gamma, beta, scale, shift);
    k_gemm_out<<<N_PAD / 64, 256, 0, stream>>>(x2, Wt, b, scale, shift, gids, x_out, phis_b);
    k_phifin<<<(N_GRAPHS * CH + 255) / 256, 256, 0, stream>>>(phis_b, phis);
}

// Round 7
// 271.133 us; speedup vs baseline: 1.2077x; 1.0996x over previous
//
#include <hip/hip_runtime.h>
#include <hip/hip_bf16.h>

#define N_NODES 100000
#define N_PAD 100032         // 1563 blocks * 64 rows
#define N_EDGES 600000
#define CH 128
#define N_GRAPHS 100
#define BN_EPS 1e-5f
#define NCHUNK 391           // ceil(N_NODES/256)
#define NBUCKET 64
#define PRESCALE_BLOCKS 6250 // N_NODES*16/256

typedef __bf16 bf16x8 __attribute__((ext_vector_type(8)));
typedef float f32x4 __attribute__((ext_vector_type(4)));

__device__ __forceinline__ ushort f2bf(float f) {
    union { float f; unsigned u; } x; x.f = f;
    unsigned u = x.u;
    unsigned r = (u + 0x7fffu + ((u >> 16) & 1u)) >> 16;
    return (ushort)r;
}
__device__ __forceinline__ float bflo(unsigned p) { return __builtin_bit_cast(float, p << 16); }
__device__ __forceinline__ float bfhi(unsigned p) { return __builtin_bit_cast(float, p & 0xffff0000u); }

// ---------------------------------------------------------------------------
// CSR build
// ---------------------------------------------------------------------------
__global__ __launch_bounds__(256) void k_hist(const int* __restrict__ dst, int* __restrict__ cnt) {
    int e = blockIdx.x * 256 + threadIdx.x;
    if (e < N_EDGES) atomicAdd(&cnt[dst[e]], 1);
}

__global__ __launch_bounds__(256) void k_blockoffs(const int* __restrict__ cnt,
        int* __restrict__ gcursor, int* __restrict__ offs, int* __restrict__ cursor) {
    __shared__ int sm[256];
    __shared__ int base;
    int t = threadIdx.x;
    int i = blockIdx.x * 256 + t;
    int v = (i < N_NODES) ? cnt[i] : 0;
    sm[t] = v; __syncthreads();
    for (int off = 1; off < 256; off <<= 1) {
        int add = (t >= off) ? sm[t - off] : 0;
        __syncthreads();
        sm[t] += add;
        __syncthreads();
    }
    if (t == 255) base = atomicAdd(gcursor, sm[255]);
    __syncthreads();
    if (i < N_NODES) {
        int start = base + sm[t] - v;
        offs[i] = start;
        cursor[i] = start;
    }
}

__global__ __launch_bounds__(256) void k_fill(const int* __restrict__ src, const int* __restrict__ dst,
        int* __restrict__ cursor, int* __restrict__ esrc) {
    int e = blockIdx.x * 256 + threadIdx.x;
    if (e < N_EDGES) {
        int p = atomicAdd(&cursor[dst[e]], 1);
        esrc[p] = src[e];
    }
}

// ---------------------------------------------------------------------------
// k_prep: blocks [0,6250): xh = bf16(h*norm); blocks [6250,6314): Wt = bf16(W^T)
// ---------------------------------------------------------------------------
__global__ __launch_bounds__(256) void k_prep(const float* __restrict__ h,
        const float* __restrict__ norm, const float* __restrict__ W,
        ushort* __restrict__ xh, ushort* __restrict__ Wt) {
    if (blockIdx.x < PRESCALE_BLOCKS) {
        int t = blockIdx.x * 256 + threadIdx.x;   // N_NODES*16
        int n = t >> 4, c = (t & 15) << 3;
        float nm = norm[n];
        float4 a = *(const float4*)(h + (size_t)n * CH + c);
        float4 d = *(const float4*)(h + (size_t)n * CH + c + 4);
        uint4 o;
        o.x = (unsigned)f2bf(a.x * nm) | ((unsigned)f2bf(a.y * nm) << 16);
        o.y = (unsigned)f2bf(a.z * nm) | ((unsigned)f2bf(a.w * nm) << 16);
        o.z = (unsigned)f2bf(d.x * nm) | ((unsigned)f2bf(d.y * nm) << 16);
        o.w = (unsigned)f2bf(d.z * nm) | ((unsigned)f2bf(d.w * nm) << 16);
        *(uint4*)(xh + (size_t)n * CH + c) = o;
    } else {
        int t = (blockIdx.x - PRESCALE_BLOCKS) * 256 + threadIdx.x;  // 16384
        int k = t >> 7, o = t & 127;
        Wt[o * CH + k] = f2bf(W[t]);
    }
}

// ---------------------------------------------------------------------------
// Gather: 16 lanes/node, 8 ch/lane (uint4 = 16B). Edge loop unrolled x4.
// Pad rows [N_NODES,N_PAD) get zeros (needed for GEMM A-frags).
// ---------------------------------------------------------------------------
__global__ __launch_bounds__(256) void k_gather(const ushort* __restrict__ xh,
        const float* __restrict__ norm, const int* __restrict__ offs,
        const int* __restrict__ cnt, const int* __restrict__ esrc,
        ushort* __restrict__ x2) {
    int t = blockIdx.x * 256 + threadIdx.x;
    int n = t >> 4;
    int c = (t & 15) << 3;                 // 8 channels
    if (n >= N_PAD) return;
    int j0 = 0, e = 0;
    float nn = 0.f;
    if (n < N_NODES) { j0 = offs[n]; e = cnt[n]; nn = norm[n]; }
    float a0=0.f,a1=0.f,a2=0.f,a3=0.f,a4=0.f,a5=0.f,a6=0.f,a7=0.f;
    int j = 0;
    for (; j + 4 <= e; j += 4) {
        int s0 = esrc[j0 + j], s1 = esrc[j0 + j + 1];
        int s2 = esrc[j0 + j + 2], s3 = esrc[j0 + j + 3];
        uint4 v0 = *(const uint4*)(xh + (size_t)s0 * CH + c);
        uint4 v1 = *(const uint4*)(xh + (size_t)s1 * CH + c);
        uint4 v2 = *(const uint4*)(xh + (size_t)s2 * CH + c);
        uint4 v3 = *(const uint4*)(xh + (size_t)s3 * CH + c);
        a0 += bflo(v0.x) + bflo(v1.x) + bflo(v2.x) + bflo(v3.x);
        a1 += bfhi(v0.x) + bfhi(v1.x) + bfhi(v2.x) + bfhi(v3.x);
        a2 += bflo(v0.y) + bflo(v1.y) + bflo(v2.y) + bflo(v3.y);
        a3 += bfhi(v0.y) + bfhi(v1.y) + bfhi(v2.y) + bfhi(v3.y);
        a4 += bflo(v0.z) + bflo(v1.z) + bflo(v2.z) + bflo(v3.z);
        a5 += bfhi(v0.z) + bfhi(v1.z) + bfhi(v2.z) + bfhi(v3.z);
        a6 += bflo(v0.w) + bflo(v1.w) + bflo(v2.w) + bflo(v3.w);
        a7 += bfhi(v0.w) + bfhi(v1.w) + bfhi(v2.w) + bfhi(v3.w);
    }
    for (; j < e; j++) {
        int s = esrc[j0 + j];
        uint4 v = *(const uint4*)(xh + (size_t)s * CH + c);
        a0 += bflo(v.x); a1 += bfhi(v.x);
        a2 += bflo(v.y); a3 += bfhi(v.y);
        a4 += bflo(v.z); a5 += bfhi(v.z);
        a6 += bflo(v.w); a7 += bfhi(v.w);
    }
    uint4 o;
    o.x = (unsigned)f2bf(a0 * nn) | ((unsigned)f2bf(a1 * nn) << 16);
    o.y = (unsigned)f2bf(a2 * nn) | ((unsigned)f2bf(a3 * nn) << 16);
    o.z = (unsigned)f2bf(a4 * nn) | ((unsigned)f2bf(a5 * nn) << 16);
    o.w = (unsigned)f2bf(a6 * nn) | ((unsigned)f2bf(a7 * nn) << 16);
    *(uint4*)(x2 + (size_t)n * CH + c) = o;
}

// ---------------------------------------------------------------------------
// Single GEMM pass: y16 = bf16(relu(x2@W + b)) via LDS-staged coalesced
// stores, plus fused BN partial stats. LDS reused for stats reduction.
// ---------------------------------------------------------------------------
__global__ __launch_bounds__(256) void k_gemm(const ushort* __restrict__ x2,
        const ushort* __restrict__ Wt, const float* __restrict__ bias,
        ushort* __restrict__ y16, float* __restrict__ psum, float* __restrict__ psq) {
    __shared__ ushort ys[64 * CH];   // 16 KB; reused as float[4096] for stats

    int tid = threadIdx.x;
    int w = tid >> 6, L = tid & 63;
    int c15 = L & 15, quad = L >> 4;
    size_t n0 = (size_t)blockIdx.x * 64 + w * 16;

    const bf16x8* Arow = (const bf16x8*)(x2 + (n0 + c15) * CH);

    f32x4 acc[8] = {};
    #pragma unroll
    for (int kt = 0; kt < 4; kt++) {
        bf16x8 a = Arow[kt * 4 + quad];
        #pragma unroll
        for (int ot = 0; ot < 8; ot++) {
            const bf16x8* Brow = (const bf16x8*)(Wt + (size_t)(ot * 16 + c15) * CH);
            bf16x8 b = Brow[kt * 4 + quad];
            acc[ot] = __builtin_amdgcn_mfma_f32_16x16x32_bf16(a, b, acc[ot], 0, 0, 0);
        }
    }

    float sA[8], qA[8];
    #pragma unroll
    for (int ot = 0; ot < 8; ot++) {
        int col = ot * 16 + c15;
        float bv = bias[col];
        float s_ = 0.f, q_ = 0.f;
        #pragma unroll
        for (int r = 0; r < 4; r++) {
            size_t n = n0 + quad * 4 + r;
            float v = fmaxf(acc[ot][r] + bv, 0.f);
            ys[(w * 16 + quad * 4 + r) * CH + col] = f2bf(v);
            if (n < N_NODES) { s_ += v; q_ += v * v; }
        }
        sA[ot] = s_; qA[ot] = q_;
    }
    __syncthreads();

    // cooperative coalesced y16 store: 1024 uint4, 4 per thread
    {
        const uint4* ysv = (const uint4*)ys;
        uint4* out = (uint4*)(y16 + (size_t)blockIdx.x * 64 * CH);
        #pragma unroll
        for (int i = 0; i < 4; i++) out[tid + i * 256] = ysv[tid + i * 256];
    }
    __syncthreads();

    // stats reduction (reuse ys as float buffer: 2048 S + 2048 Q)
    float* red = (float*)ys;
    #pragma unroll
    for (int ot = 0; ot < 8; ot++) {
        red[ot * 256 + tid] = sA[ot];
        red[2048 + ot * 256 + tid] = qA[ot];
    }
    __syncthreads();

    if (tid < 128) {
        int ot = tid >> 4, cc = tid & 15;
        int col = ot * 16 + cc;
        float S = 0.f, Q = 0.f;
        #pragma unroll
        for (int g = 0; g < 16; g++) {
            int sl = (g >> 2) * 64 + (g & 3) * 16 + cc;
            S += red[ot * 256 + sl];
            Q += red[2048 + ot * 256 + sl];
        }
        int bucket = blockIdx.x & (NBUCKET - 1);
        atomicAdd(&psum[bucket * CH + col], S);
        atomicAdd(&psq[bucket * CH + col], Q);
    }
}

// ---------------------------------------------------------------------------
// finalize: BN scale/shift + zero phis (so k_bnpool can atomicAdd directly)
// ---------------------------------------------------------------------------
__global__ void k_finalize(const float* __restrict__ psum, const float* __restrict__ psq,
        const float* __restrict__ gamma, const float* __restrict__ beta,
        float* __restrict__ scale, float* __restrict__ shift, float* __restrict__ phis) {
    int t = threadIdx.x;   // 128
    float S = 0.f, Q = 0.f;
    for (int g = 0; g < NBUCKET; g++) { S += psum[g * CH + t]; Q += psq[g * CH + t]; }
    const float invN = 1.f / (float)N_NODES;
    float mean = S * invN;
    float var  = Q * invN - mean * mean;
    float sc   = gamma[t] * rsqrtf(var + BN_EPS);
    scale[t] = sc;
    shift[t] = beta[t] - mean * sc;
    for (int i = t; i < N_GRAPHS * CH; i += 128) phis[i] = 0.f;
}

// ---------------------------------------------------------------------------
// BN apply (bf16 y16 -> f32 x) + per-graph pooling.
// 256 threads = 16 row-lanes x 16 ch-groups; 256 rows/block.
// Fast path (block all one graph): LDS reduce -> 128 atomics/block.
// ---------------------------------------------------------------------------
__global__ __launch_bounds__(256) void k_bnpool(const ushort* __restrict__ y16,
        const int* __restrict__ gids, const float* __restrict__ scale,
        const float* __restrict__ shift, float* __restrict__ xout,
        float* __restrict__ phis) {
    __shared__ float smP[16][CH];   // 8 KB

    int tid = threadIdx.x;
    int cg = tid & 15, rl = tid >> 4;
    int c = cg * 8;
    int r0 = blockIdx.x * 256;
    int rbase = r0 + rl * 16;

    float4 sc0 = *(const float4*)(scale + c), sc1 = *(const float4*)(scale + c + 4);
    float4 sh0 = *(const float4*)(shift + c), sh1 = *(const float4*)(shift + c + 4);

    bool fast = (r0 + 255 < N_NODES) && (gids[r0] == gids[r0 + 255]);

    if (fast) {
        float4 p0 = make_float4(0.f,0.f,0.f,0.f), p1 = make_float4(0.f,0.f,0.f,0.f);
        for (int j = 0; j < 16; j++) {
            int r = rbase + j;
            uint4 v = *(const uint4*)(y16 + (size_t)r * CH + c);
            float4 f0, f1;
            f0.x = fmaf(bflo(v.x), sc0.x, sh0.x); f0.y = fmaf(bfhi(v.x), sc0.y, sh0.y);
            f0.z = fmaf(bflo(v.y), sc0.z, sh0.z); f0.w = fmaf(bfhi(v.y), sc0.w, sh0.w);
            f1.x = fmaf(bflo(v.z), sc1.x, sh1.x); f1.y = fmaf(bfhi(v.z), sc1.y, sh1.y);
            f1.z = fmaf(bflo(v.w), sc1.z, sh1.z); f1.w = fmaf(bfhi(v.w), sc1.w, sh1.w);
            *(float4*)(xout + (size_t)r * CH + c) = f0;
            *(float4*)(xout + (size_t)r * CH + c + 4) = f1;
            p0.x += f0.x; p0.y += f0.y; p0.z += f0.z; p0.w += f0.w;
            p1.x += f1.x; p1.y += f1.y; p1.z += f1.z; p1.w += f1.w;
        }
        *(float4*)&smP[rl][c] = p0;
        *(float4*)&smP[rl][c + 4] = p1;
        __syncthreads();
        if (tid < 128) {
            int g = gids[r0];
            float S = 0.f;
            #pragma unroll
            for (int k = 0; k < 16; k++) S += smP[k][tid];
            atomicAdd(&phis[(size_t)g * CH + tid], S);
        }
    } else {
        float p[8] = {};
        int gprev = -1;
        for (int j = 0; j < 16; j++) {
            int r = rbase + j;
            if (r >= N_NODES) break;
            int g = gids[r];
            if (g != gprev) {
                if (gprev >= 0) {
                    #pragma unroll
                    for (int k = 0; k < 8; k++) {
                        atomicAdd(&phis[(size_t)gprev * CH + c + k], p[k]);
                        p[k] = 0.f;
                    }
                }
                gprev = g;
            }
            uint4 v = *(const uint4*)(y16 + (size_t)r * CH + c);
            float f[8];
            f[0] = fmaf(bflo(v.x), sc0.x, sh0.x); f[1] = fmaf(bfhi(v.x), sc0.y, sh0.y);
            f[2] = fmaf(bflo(v.y), sc0.z, sh0.z); f[3] = fmaf(bfhi(v.y), sc0.w, sh0.w);
            f[4] = fmaf(bflo(v.z), sc1.x, sh1.x); f[5] = fmaf(bfhi(v.z), sc1.y, sh1.y);
            f[6] = fmaf(bflo(v.w), sc1.z, sh1.z); f[7] = fmaf(bfhi(v.w), sc1.w, sh1.w);
            *(float4*)(xout + (size_t)r * CH + c) = make_float4(f[0], f[1], f[2], f[3]);
            *(float4*)(xout + (size_t)r * CH + c + 4) = make_float4(f[4], f[5], f[6], f[7]);
            #pragma unroll
            for (int k = 0; k < 8; k++) p[k] += f[k];
        }
        if (gprev >= 0) {
            #pragma unroll
            for (int k = 0; k < 8; k++)
                atomicAdd(&phis[(size_t)gprev * CH + c + k], p[k]);
        }
    }
}

// ---------------------------------------------------------------------------
extern "C" void kernel_launch(void* const* d_in, const int* in_sizes, int n_in,
                              void* d_out, int out_size, void* d_ws, size_t ws_size,
                              hipStream_t stream)
{
    const float* h     = (const float*)d_in[0];
    const float* norm  = (const float*)d_in[1];
    const float* W     = (const float*)d_in[2];
    const float* b     = (const float*)d_in[3];
    const float* gamma = (const float*)d_in[4];
    const float* beta  = (const float*)d_in[5];
    const int*   src   = (const int*)d_in[6];
    const int*   dst   = (const int*)d_in[7];
    const int*   gids  = (const int*)d_in[8];

    float* x_out = (float*)d_out;                       // [N,128]
    float* phis  = x_out + (size_t)N_NODES * CH;        // [100,128]

    ushort* xh   = (ushort*)d_ws;                       // [N,128] bf16 h*norm
    ushort* x2   = xh + (size_t)N_NODES * CH;           // [N_PAD,128] bf16 agg
    ushort* y16  = x2 + (size_t)N_PAD * CH;             // [N_PAD,128] bf16 relu(xW+b)
    ushort* Wt   = y16 + (size_t)N_PAD * CH;            // [128,128] bf16 W^T
    // ---- zeroed region (single memset) ----
    int*   cnt     = (int*)(Wt + CH * CH);              // [N]
    int*   gcursor = cnt + N_NODES;                     // [1]
    float* psum    = (float*)(gcursor + 1);             // [64,128]
    float* psq     = psum + NBUCKET * CH;               // [64,128]
    // ---- end zeroed region ----
    int*   offs    = (int*)(psq + NBUCKET * CH);        // [N]
    int*   cursor  = offs + N_NODES;                    // [N]
    int*   esrc    = cursor + N_NODES;                  // [E]
    float* scale   = (float*)(esrc + N_EDGES);          // [128]
    float* shift   = scale + CH;                        // [128]

    hipMemsetAsync(cnt, 0, (size_t)(N_NODES + 1 + 2 * NBUCKET * CH) * sizeof(int), stream);

    k_hist<<<(N_EDGES + 255) / 256, 256, 0, stream>>>(dst, cnt);
    k_blockoffs<<<NCHUNK, 256, 0, stream>>>(cnt, gcursor, offs, cursor);
    k_fill<<<(N_EDGES + 255) / 256, 256, 0, stream>>>(src, dst, cursor, esrc);
    k_prep<<<PRESCALE_BLOCKS + 64, 256, 0, stream>>>(h, norm, W, xh, Wt);
    k_gather<<<(N_PAD * 16) / 256, 256, 0, stream>>>(xh, norm, offs, cnt, esrc, x2);
    k_gemm<<<N_PAD / 64, 256, 0, stream>>>(x2, Wt, b, y16, psum, psq);
    k_finalize<<<1, 128, 0, stream>>>(psum, psq, gamma, beta, scale, shift, phis);
    k_bnpool<<<(N_NODES + 255) / 256, 256, 0, stream>>>(y16, gids, scale, shift, x_out, phis);
}

// Round 8
// 259.346 us; speedup vs baseline: 1.2626x; 1.0455x over previous
//
#include <hip/hip_runtime.h>
#include <hip/hip_bf16.h>

#define N_NODES 100000
#define N_PAD 100096         // 782 blocks * 128 rows
#define N_EDGES 600000
#define CH 128
#define N_GRAPHS 100
#define BN_EPS 1e-5f
#define NCHUNK 391           // ceil(N_NODES/256)
#define NBUCKET 64
#define HIST_BLOCKS 2344     // ceil(N_EDGES/256)
#define PRESCALE_BLOCKS 6250 // N_NODES*16/256

typedef __bf16 bf16x8 __attribute__((ext_vector_type(8)));
typedef float f32x4 __attribute__((ext_vector_type(4)));

__device__ __forceinline__ ushort f2bf(float f) {
    union { float f; unsigned u; } x; x.f = f;
    unsigned u = x.u;
    unsigned r = (u + 0x7fffu + ((u >> 16) & 1u)) >> 16;
    return (ushort)r;
}
__device__ __forceinline__ float bflo(unsigned p) { return __builtin_bit_cast(float, p << 16); }
__device__ __forceinline__ float bfhi(unsigned p) { return __builtin_bit_cast(float, p & 0xffff0000u); }

// ---------------------------------------------------------------------------
// k_front: [0,HIST) hist of dst; [HIST,HIST+PRESCALE) xh=bf16(h*norm);
//          rest: Wt=bf16(W^T). Independent work merged into one dispatch.
// ---------------------------------------------------------------------------
__global__ __launch_bounds__(256) void k_front(const int* __restrict__ dst,
        const float* __restrict__ h, const float* __restrict__ norm,
        const float* __restrict__ W, int* __restrict__ cnt,
        ushort* __restrict__ xh, ushort* __restrict__ Wt) {
    unsigned bid = blockIdx.x;
    if (bid < HIST_BLOCKS) {
        int e = bid * 256 + threadIdx.x;
        if (e < N_EDGES) atomicAdd(&cnt[dst[e]], 1);
    } else if (bid < HIST_BLOCKS + PRESCALE_BLOCKS) {
        int t = (bid - HIST_BLOCKS) * 256 + threadIdx.x;   // N_NODES*16
        int n = t >> 4, c = (t & 15) << 3;
        float nm = norm[n];
        float4 a = *(const float4*)(h + (size_t)n * CH + c);
        float4 d = *(const float4*)(h + (size_t)n * CH + c + 4);
        uint4 o;
        o.x = (unsigned)f2bf(a.x * nm) | ((unsigned)f2bf(a.y * nm) << 16);
        o.y = (unsigned)f2bf(a.z * nm) | ((unsigned)f2bf(a.w * nm) << 16);
        o.z = (unsigned)f2bf(d.x * nm) | ((unsigned)f2bf(d.y * nm) << 16);
        o.w = (unsigned)f2bf(d.z * nm) | ((unsigned)f2bf(d.w * nm) << 16);
        *(uint4*)(xh + (size_t)n * CH + c) = o;
    } else {
        int t = (bid - HIST_BLOCKS - PRESCALE_BLOCKS) * 256 + threadIdx.x;  // 16384
        int k = t >> 7, o = t & 127;
        Wt[o * CH + k] = f2bf(W[t]);
    }
}

// ---------------------------------------------------------------------------
__global__ __launch_bounds__(256) void k_blockoffs(const int* __restrict__ cnt,
        int* __restrict__ gcursor, int* __restrict__ offs, int* __restrict__ cursor) {
    __shared__ int sm[256];
    __shared__ int base;
    int t = threadIdx.x;
    int i = blockIdx.x * 256 + t;
    int v = (i < N_NODES) ? cnt[i] : 0;
    sm[t] = v; __syncthreads();
    for (int off = 1; off < 256; off <<= 1) {
        int add = (t >= off) ? sm[t - off] : 0;
        __syncthreads();
        sm[t] += add;
        __syncthreads();
    }
    if (t == 255) base = atomicAdd(gcursor, sm[255]);
    __syncthreads();
    if (i < N_NODES) {
        int start = base + sm[t] - v;
        offs[i] = start;
        cursor[i] = start;
    }
}

__global__ __launch_bounds__(256) void k_fill(const int* __restrict__ src, const int* __restrict__ dst,
        int* __restrict__ cursor, int* __restrict__ esrc) {
    int e = blockIdx.x * 256 + threadIdx.x;
    if (e < N_EDGES) {
        int p = atomicAdd(&cursor[dst[e]], 1);
        esrc[p] = src[e];
    }
}

// ---------------------------------------------------------------------------
// Gather: 16 lanes/node, 8 ch/lane (uint4 = 16B). Edge loop unrolled x4.
// Pad rows [N_NODES,N_PAD) get zeros (needed for GEMM A-frags).
// ---------------------------------------------------------------------------
__global__ __launch_bounds__(256) void k_gather(const ushort* __restrict__ xh,
        const float* __restrict__ norm, const int* __restrict__ offs,
        const int* __restrict__ cnt, const int* __restrict__ esrc,
        ushort* __restrict__ x2) {
    int t = blockIdx.x * 256 + threadIdx.x;
    int n = t >> 4;
    int c = (t & 15) << 3;                 // 8 channels
    if (n >= N_PAD) return;
    int j0 = 0, e = 0;
    float nn = 0.f;
    if (n < N_NODES) { j0 = offs[n]; e = cnt[n]; nn = norm[n]; }
    float a0=0.f,a1=0.f,a2=0.f,a3=0.f,a4=0.f,a5=0.f,a6=0.f,a7=0.f;
    int j = 0;
    for (; j + 4 <= e; j += 4) {
        int s0 = esrc[j0 + j], s1 = esrc[j0 + j + 1];
        int s2 = esrc[j0 + j + 2], s3 = esrc[j0 + j + 3];
        uint4 v0 = *(const uint4*)(xh + (size_t)s0 * CH + c);
        uint4 v1 = *(const uint4*)(xh + (size_t)s1 * CH + c);
        uint4 v2 = *(const uint4*)(xh + (size_t)s2 * CH + c);
        uint4 v3 = *(const uint4*)(xh + (size_t)s3 * CH + c);
        a0 += bflo(v0.x) + bflo(v1.x) + bflo(v2.x) + bflo(v3.x);
        a1 += bfhi(v0.x) + bfhi(v1.x) + bfhi(v2.x) + bfhi(v3.x);
        a2 += bflo(v0.y) + bflo(v1.y) + bflo(v2.y) + bflo(v3.y);
        a3 += bfhi(v0.y) + bfhi(v1.y) + bfhi(v2.y) + bfhi(v3.y);
        a4 += bflo(v0.z) + bflo(v1.z) + bflo(v2.z) + bflo(v3.z);
        a5 += bfhi(v0.z) + bfhi(v1.z) + bfhi(v2.z) + bfhi(v3.z);
        a6 += bflo(v0.w) + bflo(v1.w) + bflo(v2.w) + bflo(v3.w);
        a7 += bfhi(v0.w) + bfhi(v1.w) + bfhi(v2.w) + bfhi(v3.w);
    }
    for (; j < e; j++) {
        int s = esrc[j0 + j];
        uint4 v = *(const uint4*)(xh + (size_t)s * CH + c);
        a0 += bflo(v.x); a1 += bfhi(v.x);
        a2 += bflo(v.y); a3 += bfhi(v.y);
        a4 += bflo(v.z); a5 += bfhi(v.z);
        a6 += bflo(v.w); a7 += bfhi(v.w);
    }
    uint4 o;
    o.x = (unsigned)f2bf(a0 * nn) | ((unsigned)f2bf(a1 * nn) << 16);
    o.y = (unsigned)f2bf(a2 * nn) | ((unsigned)f2bf(a3 * nn) << 16);
    o.z = (unsigned)f2bf(a4 * nn) | ((unsigned)f2bf(a5 * nn) << 16);
    o.w = (unsigned)f2bf(a6 * nn) | ((unsigned)f2bf(a7 * nn) << 16);
    *(uint4*)(x2 + (size_t)n * CH + c) = o;
}

// ---------------------------------------------------------------------------
// GEMM: 128 rows/block, wave handles two 16-row tiles (B-frag register reuse).
// y16 = bf16(relu(x2@W + b)) via LDS-staged coalesced stores + BN stats.
// ---------------------------------------------------------------------------
__global__ __launch_bounds__(256) void k_gemm(const ushort* __restrict__ x2,
        const ushort* __restrict__ Wt, const float* __restrict__ bias,
        ushort* __restrict__ y16, float* __restrict__ psum, float* __restrict__ psq) {
    __shared__ ushort ys[128 * CH];   // 32 KB; reused as float[4096] for stats

    int tid = threadIdx.x;
    int w = tid >> 6, L = tid & 63;
    int c15 = L & 15, quad = L >> 4;
    size_t nb = (size_t)blockIdx.x * 128 + w * 32;   // wave's 32-row base

    const bf16x8* A0 = (const bf16x8*)(x2 + (nb + c15) * CH);
    const bf16x8* A1 = (const bf16x8*)(x2 + (nb + 16 + c15) * CH);

    f32x4 acc0[8] = {}, acc1[8] = {};
    #pragma unroll
    for (int kt = 0; kt < 4; kt++) {
        bf16x8 a0 = A0[kt * 4 + quad];
        bf16x8 a1 = A1[kt * 4 + quad];
        #pragma unroll
        for (int ot = 0; ot < 8; ot++) {
            bf16x8 b = *(const bf16x8*)(Wt + (size_t)(ot * 16 + c15) * CH + kt * 32 + quad * 8);
            acc0[ot] = __builtin_amdgcn_mfma_f32_16x16x32_bf16(a0, b, acc0[ot], 0, 0, 0);
            acc1[ot] = __builtin_amdgcn_mfma_f32_16x16x32_bf16(a1, b, acc1[ot], 0, 0, 0);
        }
    }

    float sA[8], qA[8];
    #pragma unroll
    for (int ot = 0; ot < 8; ot++) {
        int col = ot * 16 + c15;
        float bv = bias[col];
        float s_ = 0.f, q_ = 0.f;
        #pragma unroll
        for (int r = 0; r < 4; r++) {
            size_t n = nb + quad * 4 + r;
            float v = fmaxf(acc0[ot][r] + bv, 0.f);
            ys[(w * 32 + quad * 4 + r) * CH + col] = f2bf(v);
            if (n < N_NODES) { s_ += v; q_ += v * v; }
            size_t n2 = n + 16;
            float v2 = fmaxf(acc1[ot][r] + bv, 0.f);
            ys[(w * 32 + 16 + quad * 4 + r) * CH + col] = f2bf(v2);
            if (n2 < N_NODES) { s_ += v2; q_ += v2 * v2; }
        }
        sA[ot] = s_; qA[ot] = q_;
    }
    __syncthreads();

    // cooperative coalesced y16 store: 2048 uint4, 8 per thread
    {
        const uint4* ysv = (const uint4*)ys;
        uint4* out = (uint4*)(y16 + (size_t)blockIdx.x * 128 * CH);
        #pragma unroll
        for (int i = 0; i < 8; i++) out[tid + i * 256] = ysv[tid + i * 256];
    }
    __syncthreads();

    // stats reduction (reuse ys as float buffer: 2048 S + 2048 Q)
    float* red = (float*)ys;
    #pragma unroll
    for (int ot = 0; ot < 8; ot++) {
        red[ot * 256 + tid] = sA[ot];
        red[2048 + ot * 256 + tid] = qA[ot];
    }
    __syncthreads();

    if (tid < 128) {
        int ot = tid >> 4, cc = tid & 15;
        int col = ot * 16 + cc;
        float S = 0.f, Q = 0.f;
        #pragma unroll
        for (int g = 0; g < 16; g++) {
            int sl = (g >> 2) * 64 + (g & 3) * 16 + cc;
            S += red[ot * 256 + sl];
            Q += red[2048 + ot * 256 + sl];
        }
        int bucket = blockIdx.x & (NBUCKET - 1);
        atomicAdd(&psum[bucket * CH + col], S);
        atomicAdd(&psq[bucket * CH + col], Q);
    }
}

// ---------------------------------------------------------------------------
__global__ void k_finalize(const float* __restrict__ psum, const float* __restrict__ psq,
        const float* __restrict__ gamma, const float* __restrict__ beta,
        float* __restrict__ scale, float* __restrict__ shift, float* __restrict__ phis) {
    int t = threadIdx.x;   // 128
    float S = 0.f, Q = 0.f;
    for (int g = 0; g < NBUCKET; g++) { S += psum[g * CH + t]; Q += psq[g * CH + t]; }
    const float invN = 1.f / (float)N_NODES;
    float mean = S * invN;
    float var  = Q * invN - mean * mean;
    float sc   = gamma[t] * rsqrtf(var + BN_EPS);
    scale[t] = sc;
    shift[t] = beta[t] - mean * sc;
    for (int i = t; i < N_GRAPHS * CH; i += 128) phis[i] = 0.f;
}

// ---------------------------------------------------------------------------
// BN apply (bf16 y16 -> f32 x) + per-graph pooling.
// ---------------------------------------------------------------------------
__global__ __launch_bounds__(256) void k_bnpool(const ushort* __restrict__ y16,
        const int* __restrict__ gids, const float* __restrict__ scale,
        const float* __restrict__ shift, float* __restrict__ xout,
        float* __restrict__ phis) {
    __shared__ float smP[16][CH];   // 8 KB

    int tid = threadIdx.x;
    int cg = tid & 15, rl = tid >> 4;
    int c = cg * 8;
    int r0 = blockIdx.x * 256;
    int rbase = r0 + rl * 16;

    float4 sc0 = *(const float4*)(scale + c), sc1 = *(const float4*)(scale + c + 4);
    float4 sh0 = *(const float4*)(shift + c), sh1 = *(const float4*)(shift + c + 4);

    bool fast = (r0 + 255 < N_NODES) && (gids[r0] == gids[r0 + 255]);

    if (fast) {
        float4 p0 = make_float4(0.f,0.f,0.f,0.f), p1 = make_float4(0.f,0.f,0.f,0.f);
        for (int j = 0; j < 16; j++) {
            int r = rbase + j;
            uint4 v = *(const uint4*)(y16 + (size_t)r * CH + c);
            float4 f0, f1;
            f0.x = fmaf(bflo(v.x), sc0.x, sh0.x); f0.y = fmaf(bfhi(v.x), sc0.y, sh0.y);
            f0.z = fmaf(bflo(v.y), sc0.z, sh0.z); f0.w = fmaf(bfhi(v.y), sc0.w, sh0.w);
            f1.x = fmaf(bflo(v.z), sc1.x, sh1.x); f1.y = fmaf(bfhi(v.z), sc1.y, sh1.y);
            f1.z = fmaf(bflo(v.w), sc1.z, sh1.z); f1.w = fmaf(bfhi(v.w), sc1.w, sh1.w);
            *(float4*)(xout + (size_t)r * CH + c) = f0;
            *(float4*)(xout + (size_t)r * CH + c + 4) = f1;
            p0.x += f0.x; p0.y += f0.y; p0.z += f0.z; p0.w += f0.w;
            p1.x += f1.x; p1.y += f1.y; p1.z += f1.z; p1.w += f1.w;
        }
        *(float4*)&smP[rl][c] = p0;
        *(float4*)&smP[rl][c + 4] = p1;
        __syncthreads();
        if (tid < 128) {
            int g = gids[r0];
            float S = 0.f;
            #pragma unroll
            for (int k = 0; k < 16; k++) S += smP[k][tid];
            atomicAdd(&phis[(size_t)g * CH + tid], S);
        }
    } else {
        float p[8] = {};
        int gprev = -1;
        for (int j = 0; j < 16; j++) {
            int r = rbase + j;
            if (r >= N_NODES) break;
            int g = gids[r];
            if (g != gprev) {
                if (gprev >= 0) {
                    #pragma unroll
                    for (int k = 0; k < 8; k++) {
                        atomicAdd(&phis[(size_t)gprev * CH + c + k], p[k]);
                        p[k] = 0.f;
                    }
                }
                gprev = g;
            }
            uint4 v = *(const uint4*)(y16 + (size_t)r * CH + c);
            float f[8];
            f[0] = fmaf(bflo(v.x), sc0.x, sh0.x); f[1] = fmaf(bfhi(v.x), sc0.y, sh0.y);
            f[2] = fmaf(bflo(v.y), sc0.z, sh0.z); f[3] = fmaf(bfhi(v.y), sc0.w, sh0.w);
            f[4] = fmaf(bflo(v.z), sc1.x, sh1.x); f[5] = fmaf(bfhi(v.z), sc1.y, sh1.y);
            f[6] = fmaf(bflo(v.w), sc1.z, sh1.z); f[7] = fmaf(bfhi(v.w), sc1.w, sh1.w);
            *(float4*)(xout + (size_t)r * CH + c) = make_float4(f[0], f[1], f[2], f[3]);
            *(float4*)(xout + (size_t)r * CH + c + 4) = make_float4(f[4], f[5], f[6], f[7]);
            #pragma unroll
            for (int k = 0; k < 8; k++) p[k] += f[k];
        }
        if (gprev >= 0) {
            #pragma unroll
            for (int k = 0; k < 8; k++)
                atomicAdd(&phis[(size_t)gprev * CH + c + k], p[k]);
        }
    }
}

// ---------------------------------------------------------------------------
extern "C" void kernel_launch(void* const* d_in, const int* in_sizes, int n_in,
                              void* d_out, int out_size, void* d_ws, size_t ws_size,
                              hipStream_t stream)
{
    const float* h     = (const float*)d_in[0];
    const float* norm  = (const float*)d_in[1];
    const float* W     = (const float*)d_in[2];
    const float* b     = (const float*)d_in[3];
    const float* gamma = (const float*)d_in[4];
    const float* beta  = (const float*)d_in[5];
    const int*   src   = (const int*)d_in[6];
    const int*   dst   = (const int*)d_in[7];
    const int*   gids  = (const int*)d_in[8];

    float* x_out = (float*)d_out;                       // [N,128]
    float* phis  = x_out + (size_t)N_NODES * CH;        // [100,128]

    ushort* xh   = (ushort*)d_ws;                       // [N,128] bf16 h*norm
    ushort* x2   = xh + (size_t)N_NODES * CH;           // [N_PAD,128] bf16 agg
    ushort* y16  = x2 + (size_t)N_PAD * CH;             // [N_PAD,128] bf16 relu(xW+b)
    ushort* Wt   = y16 + (size_t)N_PAD * CH;            // [128,128] bf16 W^T
    // ---- zeroed region (single memset) ----
    int*   cnt     = (int*)(Wt + CH * CH);              // [N]
    int*   gcursor = cnt + N_NODES;                     // [1]
    float* psum    = (float*)(gcursor + 1);             // [64,128]
    float* psq     = psum + NBUCKET * CH;               // [64,128]
    // ---- end zeroed region ----
    int*   offs    = (int*)(psq + NBUCKET * CH);        // [N]
    int*   cursor  = offs + N_NODES;                    // [N]
    int*   esrc    = cursor + N_NODES;                  // [E]
    float* scale   = (float*)(esrc + N_EDGES);          // [128]
    float* shift   = scale + CH;                        // [128]

    hipMemsetAsync(cnt, 0, (size_t)(N_NODES + 1 + 2 * NBUCKET * CH) * sizeof(int), stream);

    k_front<<<HIST_BLOCKS + PRESCALE_BLOCKS + 64, 256, 0, stream>>>(dst, h, norm, W, cnt, xh, Wt);
    k_blockoffs<<<NCHUNK, 256, 0, stream>>>(cnt, gcursor, offs, cursor);
    k_fill<<<(N_EDGES + 255) / 256, 256, 0, stream>>>(src, dst, cursor, esrc);
    k_gather<<<N_PAD / 16, 256, 0, stream>>>(xh, norm, offs, cnt, esrc, x2);
    k_gemm<<<N_PAD / 128, 256, 0, stream>>>(x2, Wt, b, y16, psum, psq);
    k_finalize<<<1, 128, 0, stream>>>(psum, psq, gamma, beta, scale, shift, phis);
    k_bnpool<<<(N_NODES + 255) / 256, 256, 0, stream>>>(y16, gids, scale, shift, x_out, phis);
}